// Round 3
// baseline (429.932 us; speedup 1.0000x reference)
//
#include <hip/hip_runtime.h>
#include <hip/hip_bf16.h>

// RNN-T joint network. B=4 T=256 U=64 D=512 J=512 V=1024.
//   P_enc = enc @ W_enc^T + b_enc   (1024 x 512)  fp32 in ws
//   P_dec = dec @ W_dec^T           (256  x 512)  fp32 in ws
//   H[m]  = tanh(P_enc[m>>6] + P_dec[(m>>14)*64 + (m&63)])   (65536 x 512) bf16
//   out   = H @ W_out^T + b_out     (65536 x 1024) fp32  <-- fp32 out (round-2 fix)
//
// Inputs may be fp32 or bf16 (detected at runtime per tensor); normalized to
// bf16 copies in ws for the MFMA pipeline. Output written as fp32.

typedef __attribute__((ext_vector_type(8))) short short8;     // 8 bf16
typedef __attribute__((ext_vector_type(4))) float f32x4;
typedef __attribute__((ext_vector_type(4))) unsigned short u16x4;

#define SZ0 524288
#define SZ1 131072
#define SZ2 262144
#define SZ3 512
#define SZ4 262144
#define SZ5 524288
#define SZ6 1024
#define CU0 0
#define CU1 524288
#define CU2 655360
#define CU3 917504
#define CU4 918016
#define CU5 1180160
#define CU6 1704448
#define CTOT 1705472

// ---------------------------------------------------------------------------
// Runtime dtype detection: scan each tensor's first <=1024 ushorts as bf16.
// fp32 buffers expose random mantissa bytes as bf16 exponents >= 0x8E w.h.p.;
// genuine bf16 N(0,1)/uniform data never exceeds |v|~6. flags[t]=1 -> fp32.
// ---------------------------------------------------------------------------
__global__ void detect_kernel(const void* p0, const void* p1, const void* p2,
                              const void* p3, const void* p4, const void* p5,
                              const void* p6, int* flags) {
  const void* ps[7] = {p0, p1, p2, p3, p4, p5, p6};
  const int sz[7] = {SZ0, SZ1, SZ2, SZ3, SZ4, SZ5, SZ6};
  const int w = threadIdx.x >> 6;
  const int l = threadIdx.x & 63;
  if (w >= 7) return;
  const unsigned short* u = (const unsigned short*)ps[w];
  const int lim = sz[w] < 1024 ? sz[w] : 1024;
  int bad = 0;
  for (int j = l; j < lim; j += 64) {
    const unsigned e = (u[j] >> 7) & 0xFFu;
    if (e >= 0x8Eu) bad = 1;
  }
  const unsigned long long b = __ballot(bad);
  if (l == 0) flags[w] = (b != 0ULL) ? 1 : 0;
}

// Normalize all 7 inputs into one contiguous bf16 blob.
__global__ __launch_bounds__(256) void convert_kernel(
    const void* p0, const void* p1, const void* p2, const void* p3,
    const void* p4, const void* p5, const void* p6,
    const int* __restrict__ flags, __hip_bfloat16* __restrict__ dst) {
  const int gid = blockIdx.x * 256 + threadIdx.x;
  if (gid >= CTOT) return;
  int t, local;
  const void* p;
  if (gid < CU1)      { t = 0; local = gid - CU0; p = p0; }
  else if (gid < CU2) { t = 1; local = gid - CU1; p = p1; }
  else if (gid < CU3) { t = 2; local = gid - CU2; p = p2; }
  else if (gid < CU4) { t = 3; local = gid - CU3; p = p3; }
  else if (gid < CU5) { t = 4; local = gid - CU4; p = p4; }
  else if (gid < CU6) { t = 5; local = gid - CU5; p = p5; }
  else                { t = 6; local = gid - CU6; p = p6; }
  __hip_bfloat16 v;
  if (flags[t])
    v = __float2bfloat16(((const float*)p)[local]);
  else
    v = ((const __hip_bfloat16*)p)[local];
  dst[gid] = v;
}

// ---------------------------------------------------------------------------
// m97-structure GEMM: C[M,N] = A[M,K] * B[N,K]^T (+bias), A/B bf16 K-contig.
// 128x128 tile, BK=64, 4 waves 2x2, each wave 4x4 of 16x16x32 MFMA.
// OUT_BF16 selects bf16 vs fp32 store.
// ---------------------------------------------------------------------------
template <bool OUT_BF16>
__global__ __launch_bounds__(256) void gemm_bt(
    const __hip_bfloat16* __restrict__ A, const __hip_bfloat16* __restrict__ Bw,
    const __hip_bfloat16* __restrict__ bias, void* __restrict__ Cv,
    int M, int N, int K) {
  __shared__ __align__(16) __hip_bfloat16 sA[128 * 64];
  __shared__ __align__(16) __hip_bfloat16 sB[128 * 64];

  const int tid = threadIdx.x;
  const int w = tid >> 6;
  const int l = tid & 63;
  const int ntiles = N >> 7;
  const int mt = blockIdx.x / ntiles;
  const int nt = blockIdx.x % ntiles;
  const int m0 = mt << 7;
  const int n0 = nt << 7;
  const int wm = (w >> 1) << 6;
  const int wn = (w & 1) << 6;
  const int r16 = l & 15;
  const int q = l >> 4;

  f32x4 acc[4][4] = {};

  const int srow_in = l >> 3;
  const int scol = (l & 7) << 3;

  for (int k0 = 0; k0 < K; k0 += 64) {
#pragma unroll
    for (int i = 0; i < 4; ++i) {
      const int c = (w << 2) + i;
      const int row = (c << 3) + srow_in;
      const __hip_bfloat16* gA = A + (size_t)(m0 + row) * K + k0 + scol;
      const __hip_bfloat16* gB = Bw + (size_t)(n0 + row) * K + k0 + scol;
      __builtin_amdgcn_global_load_lds(
          (const __attribute__((address_space(1))) void*)gA,
          (__attribute__((address_space(3))) void*)(sA + (c << 9) + (l << 3)),
          16, 0, 0);
      __builtin_amdgcn_global_load_lds(
          (const __attribute__((address_space(1))) void*)gB,
          (__attribute__((address_space(3))) void*)(sB + (c << 9) + (l << 3)),
          16, 0, 0);
    }
    __syncthreads();

#pragma unroll
    for (int kk = 0; kk < 2; ++kk) {
      const int kc = (kk << 5) + (q << 3);
      short8 af[4], bf[4];
#pragma unroll
      for (int mi = 0; mi < 4; ++mi)
        af[mi] = *(const short8*)(sA + (wm + (mi << 4) + r16) * 64 + kc);
#pragma unroll
      for (int ni = 0; ni < 4; ++ni)
        bf[ni] = *(const short8*)(sB + (wn + (ni << 4) + r16) * 64 + kc);
#pragma unroll
      for (int mi = 0; mi < 4; ++mi)
#pragma unroll
        for (int ni = 0; ni < 4; ++ni)
          acc[mi][ni] = __builtin_amdgcn_mfma_f32_16x16x32_bf16(
              af[mi], bf[ni], acc[mi][ni], 0, 0, 0);
    }
    __syncthreads();
  }

  // C/D layout: col = lane&15, row = quad*4 + reg.
  __hip_bfloat16* outB = (__hip_bfloat16*)Cv;
  float* outF = (float*)Cv;
#pragma unroll
  for (int ni = 0; ni < 4; ++ni) {
    const int col = n0 + wn + (ni << 4) + r16;
    const float bc = bias ? __bfloat162float(bias[col]) : 0.0f;
#pragma unroll
    for (int mi = 0; mi < 4; ++mi) {
      const int rowb = m0 + wm + (mi << 4) + (q << 2);
#pragma unroll
      for (int i = 0; i < 4; ++i) {
        const float v = acc[mi][ni][i] + bc;
        if (OUT_BF16)
          outB[(size_t)(rowb + i) * N + col] = __float2bfloat16(v);
        else
          outF[(size_t)(rowb + i) * N + col] = v;
      }
    }
  }
}

// ---------------------------------------------------------------------------
// H[m][k] = tanh(Pe[m>>6][k] + Pd[(m>>14)*64 + (m&63)][k]), bf16.
// tanh(x) = 1 - 2/(exp(2x)+1) (exact identity; saturates cleanly).
// ---------------------------------------------------------------------------
__global__ __launch_bounds__(256) void h_kernel(
    const float* __restrict__ Pe, const float* __restrict__ Pd,
    __hip_bfloat16* __restrict__ H, int total4) {
  const int idx = blockIdx.x * blockDim.x + threadIdx.x;
  if (idx >= total4) return;
  const int m = idx >> 7;
  const int k = (idx & 127) << 2;
  const int e = m >> 6;
  const int d = ((m >> 14) << 6) + (m & 63);
  const f32x4 pe = *(const f32x4*)(Pe + (size_t)e * 512 + k);
  const f32x4 pd = *(const f32x4*)(Pd + (size_t)d * 512 + k);
  u16x4 o;
#pragma unroll
  for (int j = 0; j < 4; ++j) {
    const float s = pe[j] + pd[j];
    const float t = 1.0f - 2.0f / (__expf(2.0f * s) + 1.0f);
    const __hip_bfloat16 hb = __float2bfloat16(t);
    o[j] = *(const unsigned short*)&hb;
  }
  *(u16x4*)(H + (size_t)idx * 4) = o;
}

// ---------------------------------------------------------------------------
// Fallback main GEMM (only if ws < 72MB): tanh fused into A-tile staging.
// M=65536, N=1024, K=512 fixed. fp32 out.
// ---------------------------------------------------------------------------
__global__ __launch_bounds__(256) void gemm_fused(
    const float* __restrict__ Pe, const float* __restrict__ Pd,
    const __hip_bfloat16* __restrict__ Bw,
    const __hip_bfloat16* __restrict__ bias, float* __restrict__ out) {
  __shared__ __align__(16) __hip_bfloat16 sA[128 * 64];
  __shared__ __align__(16) __hip_bfloat16 sB[128 * 64];
  const int tid = threadIdx.x;
  const int w = tid >> 6;
  const int l = tid & 63;
  const int mt = blockIdx.x >> 3;
  const int nt = blockIdx.x & 7;
  const int m0 = mt << 7;
  const int n0 = nt << 7;
  const int wm = (w >> 1) << 6;
  const int wn = (w & 1) << 6;
  const int r16 = l & 15;
  const int q = l >> 4;
  f32x4 acc[4][4] = {};
  const int arow = tid >> 3;
  const int acol = (tid & 7) << 3;

  for (int k0 = 0; k0 < 512; k0 += 64) {
#pragma unroll
    for (int i = 0; i < 4; ++i) {
      const int c = (w << 2) + i;
      const int row = (c << 3) + (l >> 3);
      const int col = (l & 7) << 3;
      __builtin_amdgcn_global_load_lds(
          (const __attribute__((address_space(1))) void*)(
              Bw + (size_t)(n0 + row) * 512 + k0 + col),
          (__attribute__((address_space(3))) void*)(sB + (c << 9) + (l << 3)),
          16, 0, 0);
    }
#pragma unroll
    for (int c2 = 0; c2 < 4; ++c2) {
      const int row = arow + (c2 << 5);
      const int m = m0 + row;
      const int e = m >> 6;
      const int dd = ((m >> 14) << 6) | (m & 63);
      const float* pe = Pe + (size_t)e * 512 + k0 + acol;
      const float* pd = Pd + (size_t)dd * 512 + k0 + acol;
      const f32x4 e0 = *(const f32x4*)pe, e1 = *(const f32x4*)(pe + 4);
      const f32x4 g0 = *(const f32x4*)pd, g1 = *(const f32x4*)(pd + 4);
      short8 hv;
#pragma unroll
      for (int j = 0; j < 4; ++j) {
        float s = e0[j] + g0[j];
        float t = 1.0f - 2.0f / (__expf(2.0f * s) + 1.0f);
        __hip_bfloat16 hb = __float2bfloat16(t);
        hv[j] = *(const short*)&hb;
        s = e1[j] + g1[j];
        t = 1.0f - 2.0f / (__expf(2.0f * s) + 1.0f);
        hb = __float2bfloat16(t);
        hv[4 + j] = *(const short*)&hb;
      }
      *(short8*)(sA + row * 64 + acol) = hv;
    }
    __syncthreads();
#pragma unroll
    for (int kk = 0; kk < 2; ++kk) {
      const int kc = (kk << 5) + (q << 3);
      short8 af[4], bf[4];
#pragma unroll
      for (int mi = 0; mi < 4; ++mi)
        af[mi] = *(const short8*)(sA + (wm + (mi << 4) + r16) * 64 + kc);
#pragma unroll
      for (int ni = 0; ni < 4; ++ni)
        bf[ni] = *(const short8*)(sB + (wn + (ni << 4) + r16) * 64 + kc);
#pragma unroll
      for (int mi = 0; mi < 4; ++mi)
#pragma unroll
        for (int ni = 0; ni < 4; ++ni)
          acc[mi][ni] = __builtin_amdgcn_mfma_f32_16x16x32_bf16(
              af[mi], bf[ni], acc[mi][ni], 0, 0, 0);
    }
    __syncthreads();
  }

#pragma unroll
  for (int ni = 0; ni < 4; ++ni) {
    const int col = n0 + wn + (ni << 4) + r16;
    const float bc = __bfloat162float(bias[col]);
#pragma unroll
    for (int mi = 0; mi < 4; ++mi) {
      const int rowb = m0 + wm + (mi << 4) + (q << 2);
#pragma unroll
      for (int i = 0; i < 4; ++i)
        out[(size_t)(rowb + i) * 1024 + col] = acc[mi][ni][i] + bc;
    }
  }
}

// ---------------------------------------------------------------------------
extern "C" void kernel_launch(void* const* d_in, const int* in_sizes, int n_in,
                              void* d_out, int out_size, void* d_ws,
                              size_t ws_size, hipStream_t stream) {
  // ws layout (bytes):
  //   0      : flags (7 ints)
  //   256    : bf16 input copies (CTOT*2 = 3.26 MB)
  //   4 MB   : Pe fp32 (2 MB)
  //   6 MB   : Pd fp32 (0.5 MB)
  //   8 MB   : H bf16 (64 MiB)  [only if ws_size >= 72 MiB]
  char* ws = (char*)d_ws;
  int* flags = (int*)ws;
  __hip_bfloat16* cp = (__hip_bfloat16*)(ws + 256);
  float* Pe = (float*)(ws + (4ull << 20));
  float* Pd = (float*)(ws + (6ull << 20));
  __hip_bfloat16* H = (__hip_bfloat16*)(ws + (8ull << 20));
  const bool haveH = ws_size >= (72ull << 20);

  detect_kernel<<<dim3(1), dim3(512), 0, stream>>>(
      d_in[0], d_in[1], d_in[2], d_in[3], d_in[4], d_in[5], d_in[6], flags);
  convert_kernel<<<dim3((CTOT + 255) / 256), dim3(256), 0, stream>>>(
      d_in[0], d_in[1], d_in[2], d_in[3], d_in[4], d_in[5], d_in[6], flags, cp);

  const __hip_bfloat16* enc_c = cp + CU0;
  const __hip_bfloat16* dec_c = cp + CU1;
  const __hip_bfloat16* Wenc_c = cp + CU2;
  const __hip_bfloat16* benc_c = cp + CU3;
  const __hip_bfloat16* Wdec_c = cp + CU4;
  const __hip_bfloat16* Wout_c = cp + CU5;
  const __hip_bfloat16* bout_c = cp + CU6;

  gemm_bt<false><<<dim3(32), dim3(256), 0, stream>>>(enc_c, Wenc_c, benc_c, Pe,
                                                     1024, 512, 512);
  gemm_bt<false><<<dim3(8), dim3(256), 0, stream>>>(dec_c, Wdec_c, nullptr, Pd,
                                                    256, 512, 512);
  if (haveH) {
    h_kernel<<<dim3(32768), dim3(256), 0, stream>>>(Pe, Pd, H, 8388608);
    gemm_bt<false><<<dim3(4096), dim3(256), 0, stream>>>(
        H, Wout_c, bout_c, d_out, 65536, 1024, 512);
  } else {
    gemm_fused<<<dim3(4096), dim3(256), 0, stream>>>(
        Pe, Pd, Wout_c, bout_c, (float*)d_out);
  }
}